// Round 4
// baseline (331.785 us; speedup 1.0000x reference)
//
#include <hip/hip_runtime.h>
#include <hip/hip_bf16.h>

typedef __attribute__((ext_vector_type(8))) short bf16x8;
typedef __attribute__((ext_vector_type(4))) short short4v;
typedef __attribute__((ext_vector_type(4))) float f32x4;
typedef unsigned int u32;

// ---------- helpers ----------
__device__ __forceinline__ short f2bf(float f) {
    union { float f; u32 i; } c; c.f = f;
    u32 r = c.i + 0x7FFFu + ((c.i >> 16) & 1u);   // RNE
    return (short)(r >> 16);
}
__device__ __forceinline__ u32 pack2bf(float lo, float hi) {
    return ((u32)(unsigned short)f2bf(hi) << 16) | (u32)(unsigned short)f2bf(lo);
}
__device__ __forceinline__ f32x4 mfma16(bf16x8 a, bf16x8 b, f32x4 c) {
    return __builtin_amdgcn_mfma_f32_16x16x32_bf16(a, b, c, 0, 0, 0);
}
// K=16 MFMA: B-operand layout (k=(lane>>4)*4+j, col=lane&15) matches the
// QK^T D-layout exactly -> P feeds PV with ZERO cross-lane movement.
__device__ __forceinline__ f32x4 mfma16k16(short4v a, short4v b, f32x4 c) {
#if __has_builtin(__builtin_amdgcn_mfma_f32_16x16x16bf16_1k)
    return __builtin_amdgcn_mfma_f32_16x16x16bf16_1k(a, b, c, 0, 0, 0);
#else
    f32x4 d = c;
    asm volatile("v_mfma_f32_16x16x16_bf16 %0, %1, %2, %0"
                 : "+v"(d) : "v"(a), "v"(b));
    return d;
#endif
}
__device__ __forceinline__ void load_lds16(const void* g, void* l) {
    __builtin_amdgcn_global_load_lds(
        (const __attribute__((address_space(1))) u32*)g,
        (__attribute__((address_space(3))) u32*)l, 16, 0, 0);
}

// ---------- fp32 -> bf16 convert (x + 4 weights fused) ----------
__global__ __launch_bounds__(256) void cvt_all_kernel(
    const float* __restrict__ x, const float* __restrict__ wq,
    const float* __restrict__ wk, const float* __restrict__ wv,
    const float* __restrict__ wo, short* __restrict__ ws) {
    const int XV = (4096 * 1024) / 4;
    const int WV = (1024 * 1024) / 4;
    int i = blockIdx.x * 256 + threadIdx.x;
    const float4* src; short4v* dst; int off;
    if (i < XV)            { src = (const float4*)x;  dst = (short4v*)(ws);           off = i; }
    else if (i < XV + WV)  { src = (const float4*)wq; dst = (short4v*)(ws + 4194304); off = i - XV; }
    else if (i < XV + 2*WV){ src = (const float4*)wk; dst = (short4v*)(ws + 5242880); off = i - XV - WV; }
    else if (i < XV + 3*WV){ src = (const float4*)wv; dst = (short4v*)(ws + 6291456); off = i - XV - 2*WV; }
    else                   { src = (const float4*)wo; dst = (short4v*)(ws + 7340032); off = i - XV - 3*WV; }
    float4 v = src[off];
    short4v o;
    o.x = f2bf(v.x); o.y = f2bf(v.y); o.z = f2bf(v.z); o.w = f2bf(v.w);
    dst[off] = o;
}

// ---------- shared GEMM mainloop: C[128x128] += A[128xK] * B[128xK]^T ----------
__device__ __forceinline__ void gemm_mainloop(
    const short* __restrict__ A, const short* __restrict__ Bm,
    short* lds, int mbase, int nbase, int wave, int lane, f32x4 acc[4][4]) {
    const int K = 1024;
    const int lr = lane & 15, lg = lane >> 4;
    const int wm = wave >> 1, wn = wave & 1;
    for (int k0 = 0; k0 < K; k0 += 64) {
        __syncthreads();
        #pragma unroll
        for (int issue = 0; issue < 4; ++issue) {
            int f = issue * 4 + wave;
            int mt = f >> 1, kc = f & 1;
            load_lds16(A  + (size_t)(mbase + mt*16 + lr)*K + (k0 + kc*32 + lg*8), lds + f*512);
            load_lds16(Bm + (size_t)(nbase + mt*16 + lr)*K + (k0 + kc*32 + lg*8), lds + 8192 + f*512);
        }
        __syncthreads();
        #pragma unroll
        for (int kc = 0; kc < 2; ++kc) {
            bf16x8 af[4], bfv[4];
            #pragma unroll
            for (int mi = 0; mi < 4; ++mi)
                af[mi] = *(const bf16x8*)(lds + ((wm*4 + mi)*2 + kc)*512 + lane*8);
            #pragma unroll
            for (int ni = 0; ni < 4; ++ni)
                bfv[ni] = *(const bf16x8*)(lds + 8192 + ((wn*4 + ni)*2 + kc)*512 + lane*8);
            #pragma unroll
            for (int mi = 0; mi < 4; ++mi)
                #pragma unroll
                for (int ni = 0; ni < 4; ++ni)
                    acc[mi][ni] = mfma16(af[mi], bfv[ni], acc[mi][ni]);
        }
    }
}

// ---------- fused QKV projection ----------
__global__ __launch_bounds__(256) void gemm_qkv_kernel(
    const short* __restrict__ xb, const short* __restrict__ wqb,
    const short* __restrict__ wkb, const short* __restrict__ wvb,
    short* __restrict__ Qh, short* __restrict__ Kh, short* __restrict__ Vt) {
    __shared__ short lds[16384];
    const int wave = threadIdx.x >> 6, lane = threadIdx.x & 63;
    const int lr = lane & 15, lg = lane >> 4;
    const int sel = blockIdx.x >> 3;
    const int nbase = (blockIdx.x & 7) * 128;
    const int mbase = blockIdx.y * 128;
    const short* Bm = (sel == 0) ? wqb : (sel == 1) ? wkb : wvb;

    f32x4 acc[4][4];
    #pragma unroll
    for (int i = 0; i < 4; ++i)
        #pragma unroll
        for (int j = 0; j < 4; ++j) acc[i][j] = f32x4{0.f, 0.f, 0.f, 0.f};

    gemm_mainloop(xb, Bm, lds, mbase, nbase, wave, lane, acc);

    const int wm = wave >> 1, wn = wave & 1;
    #pragma unroll
    for (int mi = 0; mi < 4; ++mi) {
        int m0 = mbase + wm*64 + mi*16 + lg*4;
        #pragma unroll
        for (int ni = 0; ni < 4; ++ni) {
            int nc = nbase + wn*64 + ni*16 + lr;
            int h = nc >> 6, d = nc & 63;
            f32x4 v = acc[mi][ni];
            if (sel == 2) {
                int bi = m0 >> 11, np = m0 & 2047;
                short4v o;
                o.x = f2bf(v.x); o.y = f2bf(v.y); o.z = f2bf(v.z); o.w = f2bf(v.w);
                *(short4v*)&Vt[((size_t)(bi*16 + h)*64 + d)*2048 + np] = o;
            } else {
                short* dstb = (sel == 0) ? Qh : Kh;
                float sc = (sel == 0) ? 0.125f : 1.0f;
                #pragma unroll
                for (int r = 0; r < 4; ++r) {
                    int m = m0 + r; int bi = m >> 11, np = m & 2047;
                    dstb[((size_t)(bi*16 + h)*2048 + np)*64 + d] = f2bf(v[r] * sc);
                }
            }
        }
    }
}

// ---------- output projection ----------
__global__ __launch_bounds__(256) void gemm_out_kernel(
    const short* __restrict__ AO, const short* __restrict__ wob,
    const float* __restrict__ bias, float* __restrict__ out) {
    __shared__ short lds[16384];
    const int wave = threadIdx.x >> 6, lane = threadIdx.x & 63;
    const int lr = lane & 15, lg = lane >> 4;
    const int nbase = blockIdx.x * 128;
    const int mbase = blockIdx.y * 128;

    f32x4 acc[4][4];
    #pragma unroll
    for (int i = 0; i < 4; ++i)
        #pragma unroll
        for (int j = 0; j < 4; ++j) acc[i][j] = f32x4{0.f, 0.f, 0.f, 0.f};

    gemm_mainloop(AO, wob, lds, mbase, nbase, wave, lane, acc);

    const int wm = wave >> 1, wn = wave & 1;
    #pragma unroll
    for (int mi = 0; mi < 4; ++mi) {
        int m0 = mbase + wm*64 + mi*16 + lg*4;
        #pragma unroll
        for (int ni = 0; ni < 4; ++ni) {
            int nc = nbase + wn*64 + ni*16 + lr;
            float bj = bias[nc];
            f32x4 v = acc[mi][ni];
            #pragma unroll
            for (int r = 0; r < 4; ++r)
                out[(size_t)(m0 + r)*1024 + nc] = v[r] + bj;
        }
    }
}

// ---------- balanced 2-pass adaptive-temperature attention, shuffle-free PV ----
// Balanced wave-tasks (g=p then 127-p), XCD-affine swizzle, branch-free depth-2
// register prefetch (clamped indices), unified per-tile masking, and PV via
// v_mfma_f32_16x16x16_bf16 so the QK^T output feeds PV with no cross-lane ops.
__global__ __launch_bounds__(256) void attn_kernel(
    const short* __restrict__ Qh, const short* __restrict__ Kh,
    const short* __restrict__ Vt, short* __restrict__ AO) {
    const int lane = threadIdx.x & 63;
    const int wave = threadIdx.x >> 6;
    const int bid  = blockIdx.x;             // 0..511
    const int xcd  = bid & 7;
    const int slot = bid >> 3;               // 0..63
    const int bh   = ((slot >> 4) << 3) | xcd;
    const int p    = (slot & 15) * 4 + wave; // 0..63
    const int lr = lane & 15, lg = lane >> 4;
    const short* Q = Qh + (size_t)bh * (2048 * 64);
    const short* K = Kh + (size_t)bh * (2048 * 64);
    const short* V = Vt + (size_t)bh * (64 * 2048);
    const int b = bh >> 4, h = bh & 15;
    const int kbb = lg * 4;                  // k offset within a 16-k tile

    #pragma unroll 1
    for (int gi = 0; gi < 2; ++gi) {
        const int g  = gi ? (127 - p) : p;   // 16-row q-group index
        const int qa = g * 16 + lr;

        bf16x8 qf0 = *(const bf16x8*)&Q[(size_t)qa*64 + lg*8];
        bf16x8 qf1 = *(const bf16x8*)&Q[(size_t)qa*64 + 32 + lg*8];

        const short* Kbase = &K[(size_t)lr*64 + lg*8];   // + kt*1024 per tile

        // ================= pass 1: entropy stats =================
        float s = 0.f, t = 0.f;
        {
            bf16x8 A0, A1, B0, B1;
            A0 = *(const bf16x8*)(Kbase);
            A1 = *(const bf16x8*)(Kbase + 32);
            int i1 = (g >= 1) ? 1 : 0;
            B0 = *(const bf16x8*)(Kbase + i1*1024);
            B1 = *(const bf16x8*)(Kbase + i1*1024 + 32);
            int kt = 0;
            #pragma unroll 1
            for (; kt + 1 <= g; kt += 2) {
                f32x4 d = {0.f,0.f,0.f,0.f};
                d = mfma16(A0, qf0, d); d = mfma16(A1, qf1, d);
                int ia = (kt + 2 <= g) ? kt + 2 : g;
                A0 = *(const bf16x8*)(Kbase + ia*1024);
                A1 = *(const bf16x8*)(Kbase + ia*1024 + 32);
                int kb = kt*16 + kbb;
                #pragma unroll
                for (int r = 0; r < 4; ++r) {
                    float l = (kb + r <= qa) ? d[r] : -1e30f;
                    float e = __expf(l); s += e; t += e * l;
                }
                f32x4 d2 = {0.f,0.f,0.f,0.f};
                d2 = mfma16(B0, qf0, d2); d2 = mfma16(B1, qf1, d2);
                int ib = (kt + 3 <= g) ? kt + 3 : g;
                B0 = *(const bf16x8*)(Kbase + ib*1024);
                B1 = *(const bf16x8*)(Kbase + ib*1024 + 32);
                #pragma unroll
                for (int r = 0; r < 4; ++r) {
                    float l = (kb + 16 + r <= qa) ? d2[r] : -1e30f;
                    float e = __expf(l); s += e; t += e * l;
                }
            }
            if (kt <= g) {
                f32x4 d = {0.f,0.f,0.f,0.f};
                d = mfma16(A0, qf0, d); d = mfma16(A1, qf1, d);
                int kb = kt*16 + kbb;
                #pragma unroll
                for (int r = 0; r < 4; ++r) {
                    float l = (kb + r <= qa) ? d[r] : -1e30f;
                    float e = __expf(l); s += e; t += e * l;
                }
            }
        }
        s += __shfl_xor(s, 16); t += __shfl_xor(t, 16);
        s += __shfl_xor(s, 32); t += __shfl_xor(t, 32);
        float H = __logf(s) - t / s;
        float beta = 1.f;
        if (H > 0.5f)
            beta = fmaxf((((-0.037f*H + 0.481f)*H - 2.3f)*H + 4.917f)*H - 1.791f, 1.f);

        // ================= pass 2: softmax(beta*l) and PV =================
        f32x4 o0 = {0.f,0.f,0.f,0.f}, o1 = {0.f,0.f,0.f,0.f};
        f32x4 o2 = {0.f,0.f,0.f,0.f}, o3 = {0.f,0.f,0.f,0.f};
        float s2 = 0.f;
        {
            const short* Vbase = &V[(size_t)lr*2048 + kbb];  // + kt*16 per tile
            auto TILE = [&](bf16x8 k0, bf16x8 k1, short4v v0, short4v v1,
                            short4v v2, short4v v3, int kt2) {
                f32x4 d = {0.f,0.f,0.f,0.f};
                d = mfma16(k0, qf0, d); d = mfma16(k1, qf1, d);
                int kb = kt2*16 + kbb;
                float pv[4];
                #pragma unroll
                for (int r = 0; r < 4; ++r) {
                    float l = (kb + r <= qa) ? (beta * d[r]) : -1e30f;
                    pv[r] = __expf(l); s2 += pv[r];
                }
                union { short4v s4; u32 u[2]; } pb;
                pb.u[0] = pack2bf(pv[0], pv[1]);
                pb.u[1] = pack2bf(pv[2], pv[3]);
                o0 = mfma16k16(v0, pb.s4, o0);
                o1 = mfma16k16(v1, pb.s4, o1);
                o2 = mfma16k16(v2, pb.s4, o2);
                o3 = mfma16k16(v3, pb.s4, o3);
            };
            bf16x8 KA0, KA1, KB0, KB1;
            short4v VA0, VA1, VA2, VA3, VB0, VB1, VB2, VB3;
            KA0 = *(const bf16x8*)(Kbase);
            KA1 = *(const bf16x8*)(Kbase + 32);
            VA0 = *(const short4v*)(Vbase);
            VA1 = *(const short4v*)(Vbase + 16*2048);
            VA2 = *(const short4v*)(Vbase + 32*2048);
            VA3 = *(const short4v*)(Vbase + 48*2048);
            int i1 = (g >= 1) ? 1 : 0;
            KB0 = *(const bf16x8*)(Kbase + i1*1024);
            KB1 = *(const bf16x8*)(Kbase + i1*1024 + 32);
            VB0 = *(const short4v*)(Vbase + i1*16);
            VB1 = *(const short4v*)(Vbase + 16*2048 + i1*16);
            VB2 = *(const short4v*)(Vbase + 32*2048 + i1*16);
            VB3 = *(const short4v*)(Vbase + 48*2048 + i1*16);
            int kt = 0;
            #pragma unroll 1
            for (; kt + 1 <= g; kt += 2) {
                TILE(KA0, KA1, VA0, VA1, VA2, VA3, kt);
                int ia = (kt + 2 <= g) ? kt + 2 : g;
                KA0 = *(const bf16x8*)(Kbase + ia*1024);
                KA1 = *(const bf16x8*)(Kbase + ia*1024 + 32);
                VA0 = *(const short4v*)(Vbase + ia*16);
                VA1 = *(const short4v*)(Vbase + 16*2048 + ia*16);
                VA2 = *(const short4v*)(Vbase + 32*2048 + ia*16);
                VA3 = *(const short4v*)(Vbase + 48*2048 + ia*16);
                TILE(KB0, KB1, VB0, VB1, VB2, VB3, kt + 1);
                int ib = (kt + 3 <= g) ? kt + 3 : g;
                KB0 = *(const bf16x8*)(Kbase + ib*1024);
                KB1 = *(const bf16x8*)(Kbase + ib*1024 + 32);
                VB0 = *(const short4v*)(Vbase + ib*16);
                VB1 = *(const short4v*)(Vbase + 16*2048 + ib*16);
                VB2 = *(const short4v*)(Vbase + 32*2048 + ib*16);
                VB3 = *(const short4v*)(Vbase + 48*2048 + ib*16);
            }
            if (kt <= g) TILE(KA0, KA1, VA0, VA1, VA2, VA3, kt);
        }
        s2 += __shfl_xor(s2, 16); s2 += __shfl_xor(s2, 32);
        float inv = 1.f / s2;

        size_t row = ((size_t)(b*2048 + qa))*1024 + h*64;
        f32x4 oo[4] = {o0, o1, o2, o3};
        #pragma unroll
        for (int dc = 0; dc < 4; ++dc) {
            short4v wv;
            #pragma unroll
            for (int r = 0; r < 4; ++r) wv[r] = f2bf(oo[dc][r] * inv);
            *(short4v*)&AO[row + dc*16 + lg*4] = wv;
        }
    }
}

// ---------- launch ----------
extern "C" void kernel_launch(void* const* d_in, const int* in_sizes, int n_in,
                              void* d_out, int out_size, void* d_ws, size_t ws_size,
                              hipStream_t stream) {
    const float* x  = (const float*)d_in[0];
    const float* Wq = (const float*)d_in[1];
    const float* Wk = (const float*)d_in[2];
    const float* Wv = (const float*)d_in[3];
    const float* Wo = (const float*)d_in[4];
    const float* bo = (const float*)d_in[5];
    float* out = (float*)d_out;
    short* ws = (short*)d_ws;

    short* xb  = ws;              // [4096][1024] bf16 x
    short* wqb = ws + 4194304;
    short* wkb = ws + 5242880;
    short* wvb = ws + 6291456;
    short* wob = ws + 7340032;
    short* Qh  = ws + 8388608;    // [2][16][2048][64], scaled by 0.125
    short* Kh  = ws + 12582912;   // [2][16][2048][64]
    short* Vt  = ws + 16777216;   // [2][16][64][2048]
    short* AO  = ws + 20971520;   // [4096][1024] attention output

    cvt_all_kernel<<<8192, 256, 0, stream>>>(x, Wq, Wk, Wv, Wo, ws);
    gemm_qkv_kernel<<<dim3(24, 32), 256, 0, stream>>>(xb, wqb, wkb, wvb, Qh, Kh, Vt);
    attn_kernel<<<512, 256, 0, stream>>>(Qh, Kh, Vt, AO);
    gemm_out_kernel<<<dim3(8, 32), 256, 0, stream>>>(AO, wob, bo, out);
}

// Round 5
// 162.702 us; speedup vs baseline: 2.0392x; 2.0392x over previous
//
#include <hip/hip_runtime.h>
#include <hip/hip_bf16.h>

typedef __attribute__((ext_vector_type(8))) short bf16x8;
typedef __attribute__((ext_vector_type(4))) short short4v;
typedef __attribute__((ext_vector_type(4))) float f32x4;
typedef unsigned int u32;

// ---------- helpers ----------
__device__ __forceinline__ short f2bf(float f) {
    union { float f; u32 i; } c; c.f = f;
    u32 r = c.i + 0x7FFFu + ((c.i >> 16) & 1u);   // RNE
    return (short)(r >> 16);
}
__device__ __forceinline__ u32 pack2bf(float lo, float hi) {
    return ((u32)(unsigned short)f2bf(hi) << 16) | (u32)(unsigned short)f2bf(lo);
}
__device__ __forceinline__ f32x4 mfma16(bf16x8 a, bf16x8 b, f32x4 c) {
    return __builtin_amdgcn_mfma_f32_16x16x32_bf16(a, b, c, 0, 0, 0);
}
// K=16 MFMA: B-operand layout matches QK^T D-layout -> zero-shuffle PV.
__device__ __forceinline__ f32x4 mfma16k16(short4v a, short4v b, f32x4 c) {
#if __has_builtin(__builtin_amdgcn_mfma_f32_16x16x16bf16_1k)
    return __builtin_amdgcn_mfma_f32_16x16x16bf16_1k(a, b, c, 0, 0, 0);
#else
    f32x4 d = c;
    asm volatile("v_mfma_f32_16x16x16_bf16 %0, %1, %2, %0"
                 : "+v"(d) : "v"(a), "v"(b));
    return d;
#endif
}
__device__ __forceinline__ void load_lds16(const void* g, void* l) {
    __builtin_amdgcn_global_load_lds(
        (const __attribute__((address_space(1))) u32*)g,
        (__attribute__((address_space(3))) u32*)l, 16, 0, 0);
}

// ---------- fp32 -> bf16 convert (x + 4 weights fused) ----------
__global__ __launch_bounds__(256) void cvt_all_kernel(
    const float* __restrict__ x, const float* __restrict__ wq,
    const float* __restrict__ wk, const float* __restrict__ wv,
    const float* __restrict__ wo, short* __restrict__ ws) {
    const int XV = (4096 * 1024) / 4;
    const int WV = (1024 * 1024) / 4;
    int i = blockIdx.x * 256 + threadIdx.x;
    const float4* src; short4v* dst; int off;
    if (i < XV)            { src = (const float4*)x;  dst = (short4v*)(ws);           off = i; }
    else if (i < XV + WV)  { src = (const float4*)wq; dst = (short4v*)(ws + 4194304); off = i - XV; }
    else if (i < XV + 2*WV){ src = (const float4*)wk; dst = (short4v*)(ws + 5242880); off = i - XV - WV; }
    else if (i < XV + 3*WV){ src = (const float4*)wv; dst = (short4v*)(ws + 6291456); off = i - XV - 2*WV; }
    else                   { src = (const float4*)wo; dst = (short4v*)(ws + 7340032); off = i - XV - 3*WV; }
    float4 v = src[off];
    short4v o;
    o.x = f2bf(v.x); o.y = f2bf(v.y); o.z = f2bf(v.z); o.w = f2bf(v.w);
    dst[off] = o;
}

// ---------- shared GEMM mainloop ----------
__device__ __forceinline__ void gemm_mainloop(
    const short* __restrict__ A, const short* __restrict__ Bm,
    short* lds, int mbase, int nbase, int wave, int lane, f32x4 acc[4][4]) {
    const int K = 1024;
    const int lr = lane & 15, lg = lane >> 4;
    const int wm = wave >> 1, wn = wave & 1;
    for (int k0 = 0; k0 < K; k0 += 64) {
        __syncthreads();
        #pragma unroll
        for (int issue = 0; issue < 4; ++issue) {
            int f = issue * 4 + wave;
            int mt = f >> 1, kc = f & 1;
            load_lds16(A  + (size_t)(mbase + mt*16 + lr)*K + (k0 + kc*32 + lg*8), lds + f*512);
            load_lds16(Bm + (size_t)(nbase + mt*16 + lr)*K + (k0 + kc*32 + lg*8), lds + 8192 + f*512);
        }
        __syncthreads();
        #pragma unroll
        for (int kc = 0; kc < 2; ++kc) {
            bf16x8 af[4], bfv[4];
            #pragma unroll
            for (int mi = 0; mi < 4; ++mi)
                af[mi] = *(const bf16x8*)(lds + ((wm*4 + mi)*2 + kc)*512 + lane*8);
            #pragma unroll
            for (int ni = 0; ni < 4; ++ni)
                bfv[ni] = *(const bf16x8*)(lds + 8192 + ((wn*4 + ni)*2 + kc)*512 + lane*8);
            #pragma unroll
            for (int mi = 0; mi < 4; ++mi)
                #pragma unroll
                for (int ni = 0; ni < 4; ++ni)
                    acc[mi][ni] = mfma16(af[mi], bfv[ni], acc[mi][ni]);
        }
    }
}

// ---------- fused QKV projection ----------
// V is emitted in PV-FRAGMENT order: per (bh, chunk c of 64 n-positions):
// 8KB = slot[(s*4+dc)*64 + lg2*16 + lr2] of 4 bf16, holding
// V[np = c*64 + s*16 + lg2*4 + j][d = dc*16 + lr2].
__global__ __launch_bounds__(256) void gemm_qkv_kernel(
    const short* __restrict__ xb, const short* __restrict__ wqb,
    const short* __restrict__ wkb, const short* __restrict__ wvb,
    short* __restrict__ Qh, short* __restrict__ Kh, short* __restrict__ Vf) {
    __shared__ short lds[16384];
    const int wave = threadIdx.x >> 6, lane = threadIdx.x & 63;
    const int lr = lane & 15, lg = lane >> 4;
    const int sel = blockIdx.x >> 3;
    const int nbase = (blockIdx.x & 7) * 128;
    const int mbase = blockIdx.y * 128;
    const short* Bm = (sel == 0) ? wqb : (sel == 1) ? wkb : wvb;

    f32x4 acc[4][4];
    #pragma unroll
    for (int i = 0; i < 4; ++i)
        #pragma unroll
        for (int j = 0; j < 4; ++j) acc[i][j] = f32x4{0.f, 0.f, 0.f, 0.f};

    gemm_mainloop(xb, Bm, lds, mbase, nbase, wave, lane, acc);

    const int wm = wave >> 1, wn = wave & 1;
    #pragma unroll
    for (int mi = 0; mi < 4; ++mi) {
        int m0 = mbase + wm*64 + mi*16 + lg*4;
        #pragma unroll
        for (int ni = 0; ni < 4; ++ni) {
            int nc = nbase + wn*64 + ni*16 + lr;
            int h = nc >> 6, d = nc & 63;
            f32x4 v = acc[mi][ni];
            if (sel == 2) {
                int bi = m0 >> 11, np = m0 & 2047;
                int c = np >> 6, s = (np >> 4) & 3, lg2 = (np >> 2) & 3;
                int dc = d >> 4, lr2 = d & 15;
                size_t off = ((size_t)(bi*16 + h)*32 + c)*4096
                           + (size_t)((s*4 + dc)*64 + lg2*16 + lr2)*4;
                short4v o;
                o.x = f2bf(v.x); o.y = f2bf(v.y); o.z = f2bf(v.z); o.w = f2bf(v.w);
                *(short4v*)&Vf[off] = o;
            } else {
                short* dstb = (sel == 0) ? Qh : Kh;
                float sc = (sel == 0) ? 0.125f : 1.0f;
                #pragma unroll
                for (int r = 0; r < 4; ++r) {
                    int m = m0 + r; int bi = m >> 11, np = m & 2047;
                    dstb[((size_t)(bi*16 + h)*2048 + np)*64 + d] = f2bf(v[r] * sc);
                }
            }
        }
    }
}

// ---------- output projection ----------
__global__ __launch_bounds__(256) void gemm_out_kernel(
    const short* __restrict__ AO, const short* __restrict__ wob,
    const float* __restrict__ bias, float* __restrict__ out) {
    __shared__ short lds[16384];
    const int wave = threadIdx.x >> 6, lane = threadIdx.x & 63;
    const int lr = lane & 15, lg = lane >> 4;
    const int nbase = blockIdx.x * 128;
    const int mbase = blockIdx.y * 128;

    f32x4 acc[4][4];
    #pragma unroll
    for (int i = 0; i < 4; ++i)
        #pragma unroll
        for (int j = 0; j < 4; ++j) acc[i][j] = f32x4{0.f, 0.f, 0.f, 0.f};

    gemm_mainloop(AO, wob, lds, mbase, nbase, wave, lane, acc);

    const int wm = wave >> 1, wn = wave & 1;
    #pragma unroll
    for (int mi = 0; mi < 4; ++mi) {
        int m0 = mbase + wm*64 + mi*16 + lg*4;
        #pragma unroll
        for (int ni = 0; ni < 4; ++ni) {
            int nc = nbase + wn*64 + ni*16 + lr;
            float bj = bias[nc];
            f32x4 v = acc[mi][ni];
            #pragma unroll
            for (int r = 0; r < 4; ++r)
                out[(size_t)(m0 + r)*1024 + nc] = v[r] + bj;
        }
    }
}

// ---------- LDS-staged 2-pass adaptive-temperature attention ----------
// Block = 64 q-rows (4 waves x 16), iterates 64-k chunks 0..u shared via LDS.
// K/V staged with async global_load_lds into FRAGMENT-ORDERED double buffers
// (conflict-free ds_read_b128/b64), one barrier per chunk, staging of chunk
// c+1 in flight during compute of chunk c. Interior chunks unmasked; only the
// final chunk has per-wave partial subtiles. Zero-shuffle PV via K=16 MFMA.
__global__ __launch_bounds__(256, 4) void attn_kernel(
    const short* __restrict__ Qh, const short* __restrict__ Kh,
    const short* __restrict__ Vf, short* __restrict__ AO) {
    __shared__ short lds[16384];   // shorts: K bufs [0,8192), V bufs [8192,16384)
    const int lane = threadIdx.x & 63;
    const int wave = threadIdx.x >> 6;
    const int lr = lane & 15, lg = lane >> 4;
    const int bid  = blockIdx.x;             // 0..1023
    const int xcd  = bid & 7;
    const int rest = bid >> 3;               // 0..127
    const int u    = 31 - (rest >> 2);       // heavy q-tiles dispatch first
    const int bh   = ((rest & 3) << 3) | xcd;
    const int b = bh >> 4, h = bh & 15;
    const int qbase = u*64 + wave*16;
    const int qa = qbase + lr;
    const short* Q  = Qh + (size_t)bh * (2048 * 64);
    const short* Kg = Kh + (size_t)bh * (2048 * 64);
    const short* Vg = Vf + (size_t)bh * (32 * 4096);

    bf16x8 qf0 = *(const bf16x8*)&Q[(size_t)qa*64 + lg*8];
    bf16x8 qf1 = *(const bf16x8*)&Q[(size_t)qa*64 + 32 + lg*8];

    const int fc0 = wave * 2;   // this wave's staging slots

    auto stageK = [&](int buf, int c) {
        #pragma unroll
        for (int i = 0; i < 2; ++i) {
            int fc = fc0 + i, s = fc >> 1, ch = fc & 1;
            load_lds16(Kg + ((size_t)(c*64 + s*16 + lr)*64 + ch*32 + lg*8),
                       &lds[buf*4096 + fc*512]);
        }
    };
    auto stageV = [&](int buf, int c) {
        #pragma unroll
        for (int i = 0; i < 2; ++i) {
            int fi = fc0 + i;
            load_lds16(Vg + (size_t)c*4096 + fi*512 + lane*8,
                       &lds[8192 + buf*4096 + fi*512]);
        }
    };

    // ================= pass 1: entropy stats =================
    float sm = 0.f, tm = 0.f;
    stageK(0, 0);
    #pragma unroll 1
    for (int c = 0; c <= u; ++c) {
        __syncthreads();                       // buf[c&1] ready
        if (c < u) stageK((c + 1) & 1, c + 1); // async, hidden under compute
        const int base = (c & 1) * 4096;
        #pragma unroll
        for (int s = 0; s < 4; ++s) {
            int k0 = c*64 + s*16;
            if (k0 <= qbase) {                 // wave-uniform
                bf16x8 kf0 = *(const bf16x8*)&lds[base + (s*2    )*512 + lane*8];
                bf16x8 kf1 = *(const bf16x8*)&lds[base + (s*2 + 1)*512 + lane*8];
                f32x4 d = {0.f,0.f,0.f,0.f};
                d = mfma16(kf0, qf0, d); d = mfma16(kf1, qf1, d);
                if (k0 < qbase) {
                    #pragma unroll
                    for (int r = 0; r < 4; ++r) {
                        float e = __expf(d[r]); sm += e; tm += e * d[r];
                    }
                } else {                       // diagonal subtile
                    int kb = k0 + lg*4;
                    #pragma unroll
                    for (int r = 0; r < 4; ++r) {
                        float l = (kb + r <= qa) ? d[r] : -1e30f;
                        float e = __expf(l); sm += e; tm += e * l;
                    }
                }
            }
        }
    }
    sm += __shfl_xor(sm, 16); tm += __shfl_xor(tm, 16);
    sm += __shfl_xor(sm, 32); tm += __shfl_xor(tm, 32);
    float H = __logf(sm) - tm / sm;
    float beta = 1.f;
    if (H > 0.5f)
        beta = fmaxf((((-0.037f*H + 0.481f)*H - 2.3f)*H + 4.917f)*H - 1.791f, 1.f);

    // ================= pass 2: softmax(beta*l) and PV =================
    f32x4 o0 = {0.f,0.f,0.f,0.f}, o1 = {0.f,0.f,0.f,0.f};
    f32x4 o2 = {0.f,0.f,0.f,0.f}, o3 = {0.f,0.f,0.f,0.f};
    float s2 = 0.f;
    __syncthreads();                           // pass-1 reads done; reuse bufs
    stageK(0, 0); stageV(0, 0);
    #pragma unroll 1
    for (int c = 0; c <= u; ++c) {
        __syncthreads();
        if (c < u) { stageK((c + 1) & 1, c + 1); stageV((c + 1) & 1, c + 1); }
        const int kb_ = (c & 1) * 4096;
        const int vb_ = 8192 + (c & 1) * 4096;
        #pragma unroll
        for (int s = 0; s < 4; ++s) {
            int k0 = c*64 + s*16;
            if (k0 <= qbase) {
                bf16x8 kf0 = *(const bf16x8*)&lds[kb_ + (s*2    )*512 + lane*8];
                bf16x8 kf1 = *(const bf16x8*)&lds[kb_ + (s*2 + 1)*512 + lane*8];
                f32x4 d = {0.f,0.f,0.f,0.f};
                d = mfma16(kf0, qf0, d); d = mfma16(kf1, qf1, d);
                float pv[4];
                if (k0 < qbase) {
                    #pragma unroll
                    for (int r = 0; r < 4; ++r) { pv[r] = __expf(beta * d[r]); s2 += pv[r]; }
                } else {
                    int kb = k0 + lg*4;
                    #pragma unroll
                    for (int r = 0; r < 4; ++r) {
                        pv[r] = (kb + r <= qa) ? __expf(beta * d[r]) : 0.f; s2 += pv[r];
                    }
                }
                union { short4v s4; u32 uu[2]; } pb;
                pb.uu[0] = pack2bf(pv[0], pv[1]);
                pb.uu[1] = pack2bf(pv[2], pv[3]);
                short4v vf0 = *(const short4v*)&lds[vb_ + ((s*4 + 0)*64 + lane)*4];
                short4v vf1 = *(const short4v*)&lds[vb_ + ((s*4 + 1)*64 + lane)*4];
                short4v vf2 = *(const short4v*)&lds[vb_ + ((s*4 + 2)*64 + lane)*4];
                short4v vf3 = *(const short4v*)&lds[vb_ + ((s*4 + 3)*64 + lane)*4];
                o0 = mfma16k16(vf0, pb.s4, o0);
                o1 = mfma16k16(vf1, pb.s4, o1);
                o2 = mfma16k16(vf2, pb.s4, o2);
                o3 = mfma16k16(vf3, pb.s4, o3);
            }
        }
    }
    s2 += __shfl_xor(s2, 16); s2 += __shfl_xor(s2, 32);
    float inv = 1.f / s2;

    size_t row = ((size_t)(b*2048 + qa))*1024 + h*64;
    f32x4 oo[4] = {o0, o1, o2, o3};
    #pragma unroll
    for (int dc = 0; dc < 4; ++dc) {
        short4v wv;
        #pragma unroll
        for (int r = 0; r < 4; ++r) wv[r] = f2bf(oo[dc][r] * inv);
        *(short4v*)&AO[row + dc*16 + lg*4] = wv;
    }
}

// ---------- launch ----------
extern "C" void kernel_launch(void* const* d_in, const int* in_sizes, int n_in,
                              void* d_out, int out_size, void* d_ws, size_t ws_size,
                              hipStream_t stream) {
    const float* x  = (const float*)d_in[0];
    const float* Wq = (const float*)d_in[1];
    const float* Wk = (const float*)d_in[2];
    const float* Wv = (const float*)d_in[3];
    const float* Wo = (const float*)d_in[4];
    const float* bo = (const float*)d_in[5];
    float* out = (float*)d_out;
    short* ws = (short*)d_ws;

    short* xb  = ws;              // [4096][1024] bf16 x
    short* wqb = ws + 4194304;
    short* wkb = ws + 5242880;
    short* wvb = ws + 6291456;
    short* wob = ws + 7340032;
    short* Qh  = ws + 8388608;    // [2][16][2048][64], scaled by 0.125
    short* Kh  = ws + 12582912;   // [2][16][2048][64]
    short* Vf  = ws + 16777216;   // [32 bh][32 chunks][4096] PV-fragment order
    short* AO  = ws + 20971520;   // [4096][1024] attention output

    cvt_all_kernel<<<8192, 256, 0, stream>>>(x, Wq, Wk, Wv, Wo, ws);
    gemm_qkv_kernel<<<dim3(24, 32), 256, 0, stream>>>(xb, wqb, wkb, wvb, Qh, Kh, Vf);
    attn_kernel<<<1024, 256, 0, stream>>>(Qh, Kh, Vf, AO);
    gemm_out_kernel<<<dim3(8, 32), 256, 0, stream>>>(AO, wob, bo, out);
}

// Round 6
// 158.200 us; speedup vs baseline: 2.0973x; 1.0285x over previous
//
#include <hip/hip_runtime.h>
#include <hip/hip_bf16.h>

typedef __attribute__((ext_vector_type(8))) short bf16x8;
typedef __attribute__((ext_vector_type(4))) short short4v;
typedef __attribute__((ext_vector_type(4))) float f32x4;
typedef unsigned int u32;

// ---------- helpers ----------
__device__ __forceinline__ short f2bf(float f) {
    union { float f; u32 i; } c; c.f = f;
    u32 r = c.i + 0x7FFFu + ((c.i >> 16) & 1u);   // RNE
    return (short)(r >> 16);
}
__device__ __forceinline__ u32 pack2bf(float lo, float hi) {
    return ((u32)(unsigned short)f2bf(hi) << 16) | (u32)(unsigned short)f2bf(lo);
}
__device__ __forceinline__ f32x4 mfma16(bf16x8 a, bf16x8 b, f32x4 c) {
    return __builtin_amdgcn_mfma_f32_16x16x32_bf16(a, b, c, 0, 0, 0);
}
// K=16 MFMA: B-operand layout matches QK^T D-layout -> zero-shuffle PV.
__device__ __forceinline__ f32x4 mfma16k16(short4v a, short4v b, f32x4 c) {
#if __has_builtin(__builtin_amdgcn_mfma_f32_16x16x16bf16_1k)
    return __builtin_amdgcn_mfma_f32_16x16x16bf16_1k(a, b, c, 0, 0, 0);
#else
    f32x4 d = c;
    asm volatile("v_mfma_f32_16x16x16_bf16 %0, %1, %2, %0"
                 : "+v"(d) : "v"(a), "v"(b));
    return d;
#endif
}
__device__ __forceinline__ void load_lds16(const void* g, void* l) {
    __builtin_amdgcn_global_load_lds(
        (const __attribute__((address_space(1))) u32*)g,
        (__attribute__((address_space(3))) u32*)l, 16, 0, 0);
}

// ---------- fp32 -> bf16 convert (x + 4 weights fused) ----------
__global__ __launch_bounds__(256) void cvt_all_kernel(
    const float* __restrict__ x, const float* __restrict__ wq,
    const float* __restrict__ wk, const float* __restrict__ wv,
    const float* __restrict__ wo, short* __restrict__ ws) {
    const int XV = (4096 * 1024) / 4;
    const int WV = (1024 * 1024) / 4;
    int i = blockIdx.x * 256 + threadIdx.x;
    const float4* src; short4v* dst; int off;
    if (i < XV)            { src = (const float4*)x;  dst = (short4v*)(ws);           off = i; }
    else if (i < XV + WV)  { src = (const float4*)wq; dst = (short4v*)(ws + 4194304); off = i - XV; }
    else if (i < XV + 2*WV){ src = (const float4*)wk; dst = (short4v*)(ws + 5242880); off = i - XV - WV; }
    else if (i < XV + 3*WV){ src = (const float4*)wv; dst = (short4v*)(ws + 6291456); off = i - XV - 2*WV; }
    else                   { src = (const float4*)wo; dst = (short4v*)(ws + 7340032); off = i - XV - 3*WV; }
    float4 v = src[off];
    short4v o;
    o.x = f2bf(v.x); o.y = f2bf(v.y); o.z = f2bf(v.z); o.w = f2bf(v.w);
    dst[off] = o;
}

// ---------- shared GEMM mainloop (128x128 tile) ----------
__device__ __forceinline__ void gemm_mainloop(
    const short* __restrict__ A, const short* __restrict__ Bm,
    short* lds, int mbase, int nbase, int wave, int lane, f32x4 acc[4][4]) {
    const int K = 1024;
    const int lr = lane & 15, lg = lane >> 4;
    const int wm = wave >> 1, wn = wave & 1;
    for (int k0 = 0; k0 < K; k0 += 64) {
        __syncthreads();
        #pragma unroll
        for (int issue = 0; issue < 4; ++issue) {
            int f = issue * 4 + wave;
            int mt = f >> 1, kc = f & 1;
            load_lds16(A  + (size_t)(mbase + mt*16 + lr)*K + (k0 + kc*32 + lg*8), lds + f*512);
            load_lds16(Bm + (size_t)(nbase + mt*16 + lr)*K + (k0 + kc*32 + lg*8), lds + 8192 + f*512);
        }
        __syncthreads();
        #pragma unroll
        for (int kc = 0; kc < 2; ++kc) {
            bf16x8 af[4], bfv[4];
            #pragma unroll
            for (int mi = 0; mi < 4; ++mi)
                af[mi] = *(const bf16x8*)(lds + ((wm*4 + mi)*2 + kc)*512 + lane*8);
            #pragma unroll
            for (int ni = 0; ni < 4; ++ni)
                bfv[ni] = *(const bf16x8*)(lds + 8192 + ((wn*4 + ni)*2 + kc)*512 + lane*8);
            #pragma unroll
            for (int mi = 0; mi < 4; ++mi)
                #pragma unroll
                for (int ni = 0; ni < 4; ++ni)
                    acc[mi][ni] = mfma16(af[mi], bfv[ni], acc[mi][ni]);
        }
    }
}

// ---------- fused QKV projection ----------
// Q/K epilogue goes through an LDS transpose so global stores are 16-B
// coalesced into the [bh][np][64] panel layout attn reads. V is emitted
// directly in PV-fragment order (already 512-B contiguous per wave store).
__global__ __launch_bounds__(256) void gemm_qkv_kernel(
    const short* __restrict__ xb, const short* __restrict__ wqb,
    const short* __restrict__ wkb, const short* __restrict__ wvb,
    short* __restrict__ Qh, short* __restrict__ Kh, short* __restrict__ Vf) {
    __shared__ short lds[16896];   // mainloop uses [0,16384); epilogue 128x132
    const int wave = threadIdx.x >> 6, lane = threadIdx.x & 63;
    const int lr = lane & 15, lg = lane >> 4;
    const int sel = blockIdx.x >> 3;
    const int nbase = (blockIdx.x & 7) * 128;
    const int mbase = blockIdx.y * 128;
    const short* Bm = (sel == 0) ? wqb : (sel == 1) ? wkb : wvb;

    f32x4 acc[4][4];
    #pragma unroll
    for (int i = 0; i < 4; ++i)
        #pragma unroll
        for (int j = 0; j < 4; ++j) acc[i][j] = f32x4{0.f, 0.f, 0.f, 0.f};

    gemm_mainloop(xb, Bm, lds, mbase, nbase, wave, lane, acc);

    const int wm = wave >> 1, wn = wave & 1;
    if (sel == 2) {
        #pragma unroll
        for (int mi = 0; mi < 4; ++mi) {
            int m0 = mbase + wm*64 + mi*16 + lg*4;
            #pragma unroll
            for (int ni = 0; ni < 4; ++ni) {
                int nc = nbase + wn*64 + ni*16 + lr;
                int h = nc >> 6, d = nc & 63;
                f32x4 v = acc[mi][ni];
                int bi = m0 >> 11, np = m0 & 2047;
                int c = np >> 6, s = (np >> 4) & 3, lg2 = (np >> 2) & 3;
                int dc = d >> 4, lr2 = d & 15;
                size_t off = ((size_t)(bi*16 + h)*32 + c)*4096
                           + (size_t)((s*4 + dc)*64 + lg2*16 + lr2)*4;
                short4v o;
                o.x = f2bf(v.x); o.y = f2bf(v.y); o.z = f2bf(v.z); o.w = f2bf(v.w);
                *(short4v*)&Vf[off] = o;
            }
        }
    } else {
        short* dstb = (sel == 0) ? Qh : Kh;
        const float sc = (sel == 0) ? 0.125f : 1.0f;   // fold 1/sqrt(64) into Q
        __syncthreads();   // all mainloop LDS reads done before overwrite
        #pragma unroll
        for (int mi = 0; mi < 4; ++mi) {
            int row0 = wm*64 + mi*16 + lg*4;
            #pragma unroll
            for (int ni = 0; ni < 4; ++ni) {
                int col = wn*64 + ni*16 + lr;
                f32x4 v = acc[mi][ni];
                #pragma unroll
                for (int r = 0; r < 4; ++r)
                    lds[(row0 + r)*132 + col] = f2bf(v[r] * sc);
            }
        }
        __syncthreads();
        const int h0 = nbase >> 6;
        const int tid = threadIdx.x;
        #pragma unroll
        for (int it = 0; it < 8; ++it) {
            int L = it*256 + tid;          // 0..2047
            int np_l = L >> 4;             // 0..127
            int t16 = L & 15;
            int P = t16 >> 3;              // head panel 0/1
            int c8 = (t16 & 7) * 8;        // col in shorts
            bf16x8 val = *(const bf16x8*)&lds[np_l*132 + P*64 + c8];
            int m = mbase + np_l; int bi = m >> 11, np = m & 2047;
            *(bf16x8*)&dstb[((size_t)(bi*16 + h0 + P)*2048 + np)*64 + c8] = val;
        }
    }
}

// ---------- output projection: 64x128 tile (512 blocks = 2/CU) ----------
__global__ __launch_bounds__(256) void gemm_out_kernel(
    const short* __restrict__ AO, const short* __restrict__ wob,
    const float* __restrict__ bias, float* __restrict__ out) {
    __shared__ short lds[12288];   // A 64x64k [0,4096), B 128x64k [4096,12288)
    const int K = 1024;
    const int wave = threadIdx.x >> 6, lane = threadIdx.x & 63;
    const int lr = lane & 15, lg = lane >> 4;
    const int nbase = blockIdx.x * 128;
    const int mbase = blockIdx.y * 64;
    const int wm = wave >> 1, wn = wave & 1;

    f32x4 acc[2][4];
    #pragma unroll
    for (int i = 0; i < 2; ++i)
        #pragma unroll
        for (int j = 0; j < 4; ++j) acc[i][j] = f32x4{0.f, 0.f, 0.f, 0.f};

    for (int k0 = 0; k0 < K; k0 += 64) {
        __syncthreads();
        #pragma unroll
        for (int l = 0; l < 6; ++l) {
            int f = l*4 + wave;
            if (f < 8) {
                int mt = f >> 1, kc = f & 1;
                load_lds16(AO + (size_t)(mbase + mt*16 + lr)*K + (k0 + kc*32 + lg*8),
                           lds + f*512);
            } else {
                int fb = f - 8, nt = fb >> 1, kc = fb & 1;
                load_lds16(wob + (size_t)(nbase + nt*16 + lr)*K + (k0 + kc*32 + lg*8),
                           lds + 4096 + fb*512);
            }
        }
        __syncthreads();
        #pragma unroll
        for (int kc = 0; kc < 2; ++kc) {
            bf16x8 af[2], bfv[4];
            #pragma unroll
            for (int mi = 0; mi < 2; ++mi)
                af[mi] = *(const bf16x8*)(lds + ((wm*2 + mi)*2 + kc)*512 + lane*8);
            #pragma unroll
            for (int ni = 0; ni < 4; ++ni)
                bfv[ni] = *(const bf16x8*)(lds + 4096 + ((wn*4 + ni)*2 + kc)*512 + lane*8);
            #pragma unroll
            for (int mi = 0; mi < 2; ++mi)
                #pragma unroll
                for (int ni = 0; ni < 4; ++ni)
                    acc[mi][ni] = mfma16(af[mi], bfv[ni], acc[mi][ni]);
        }
    }

    #pragma unroll
    for (int mi = 0; mi < 2; ++mi) {
        int m0 = mbase + wm*32 + mi*16 + lg*4;
        #pragma unroll
        for (int ni = 0; ni < 4; ++ni) {
            int nc = nbase + wn*64 + ni*16 + lr;
            float bj = bias[nc];
            f32x4 v = acc[mi][ni];
            #pragma unroll
            for (int r = 0; r < 4; ++r)
                out[(size_t)(m0 + r)*1024 + nc] = v[r] + bj;
        }
    }
}

// ---------- LDS-staged 2-pass adaptive-temperature attention ----------
// Block = 64 q-rows (4 waves x 16), iterates 64-k chunks 0..u shared via LDS.
// K/V staged with async global_load_lds into fragment-ordered double buffers,
// one barrier per chunk, staging of chunk c+1 in flight during compute of c.
// Zero-shuffle PV via K=16 MFMA.
__global__ __launch_bounds__(256, 4) void attn_kernel(
    const short* __restrict__ Qh, const short* __restrict__ Kh,
    const short* __restrict__ Vf, short* __restrict__ AO) {
    __shared__ short lds[16384];   // K bufs [0,8192), V bufs [8192,16384)
    const int lane = threadIdx.x & 63;
    const int wave = threadIdx.x >> 6;
    const int lr = lane & 15, lg = lane >> 4;
    const int bid  = blockIdx.x;             // 0..1023
    const int xcd  = bid & 7;
    const int rest = bid >> 3;               // 0..127
    const int u    = 31 - (rest >> 2);       // heavy q-tiles dispatch first
    const int bh   = ((rest & 3) << 3) | xcd;
    const int b = bh >> 4, h = bh & 15;
    const int qbase = u*64 + wave*16;
    const int qa = qbase + lr;
    const short* Q  = Qh + (size_t)bh * (2048 * 64);
    const short* Kg = Kh + (size_t)bh * (2048 * 64);
    const short* Vg = Vf + (size_t)bh * (32 * 4096);

    bf16x8 qf0 = *(const bf16x8*)&Q[(size_t)qa*64 + lg*8];
    bf16x8 qf1 = *(const bf16x8*)&Q[(size_t)qa*64 + 32 + lg*8];

    const int fc0 = wave * 2;   // this wave's staging slots

    auto stageK = [&](int buf, int c) {
        #pragma unroll
        for (int i = 0; i < 2; ++i) {
            int fc = fc0 + i, s = fc >> 1, ch = fc & 1;
            load_lds16(Kg + ((size_t)(c*64 + s*16 + lr)*64 + ch*32 + lg*8),
                       &lds[buf*4096 + fc*512]);
        }
    };
    auto stageV = [&](int buf, int c) {
        #pragma unroll
        for (int i = 0; i < 2; ++i) {
            int fi = fc0 + i;
            load_lds16(Vg + (size_t)c*4096 + fi*512 + lane*8,
                       &lds[8192 + buf*4096 + fi*512]);
        }
    };

    // ================= pass 1: entropy stats =================
    float sm = 0.f, tm = 0.f;
    stageK(0, 0);
    #pragma unroll 1
    for (int c = 0; c <= u; ++c) {
        __syncthreads();                       // buf[c&1] ready
        if (c < u) stageK((c + 1) & 1, c + 1); // async, hidden under compute
        const int base = (c & 1) * 4096;
        #pragma unroll
        for (int s = 0; s < 4; ++s) {
            int k0 = c*64 + s*16;
            if (k0 <= qbase) {                 // wave-uniform
                bf16x8 kf0 = *(const bf16x8*)&lds[base + (s*2    )*512 + lane*8];
                bf16x8 kf1 = *(const bf16x8*)&lds[base + (s*2 + 1)*512 + lane*8];
                f32x4 d = {0.f,0.f,0.f,0.f};
                d = mfma16(kf0, qf0, d); d = mfma16(kf1, qf1, d);
                if (k0 < qbase) {
                    #pragma unroll
                    for (int r = 0; r < 4; ++r) {
                        float e = __expf(d[r]); sm += e; tm += e * d[r];
                    }
                } else {                       // diagonal subtile
                    int kb = k0 + lg*4;
                    #pragma unroll
                    for (int r = 0; r < 4; ++r) {
                        float l = (kb + r <= qa) ? d[r] : -1e30f;
                        float e = __expf(l); sm += e; tm += e * l;
                    }
                }
            }
        }
    }
    sm += __shfl_xor(sm, 16); tm += __shfl_xor(tm, 16);
    sm += __shfl_xor(sm, 32); tm += __shfl_xor(tm, 32);
    float H = __logf(sm) - tm / sm;
    float beta = 1.f;
    if (H > 0.5f)
        beta = fmaxf((((-0.037f*H + 0.481f)*H - 2.3f)*H + 4.917f)*H - 1.791f, 1.f);

    // ================= pass 2: softmax(beta*l) and PV =================
    f32x4 o0 = {0.f,0.f,0.f,0.f}, o1 = {0.f,0.f,0.f,0.f};
    f32x4 o2 = {0.f,0.f,0.f,0.f}, o3 = {0.f,0.f,0.f,0.f};
    float s2 = 0.f;
    __syncthreads();                           // pass-1 reads done; reuse bufs
    stageK(0, 0); stageV(0, 0);
    #pragma unroll 1
    for (int c = 0; c <= u; ++c) {
        __syncthreads();
        if (c < u) { stageK((c + 1) & 1, c + 1); stageV((c + 1) & 1, c + 1); }
        const int kb_ = (c & 1) * 4096;
        const int vb_ = 8192 + (c & 1) * 4096;
        #pragma unroll
        for (int s = 0; s < 4; ++s) {
            int k0 = c*64 + s*16;
            if (k0 <= qbase) {
                bf16x8 kf0 = *(const bf16x8*)&lds[kb_ + (s*2    )*512 + lane*8];
                bf16x8 kf1 = *(const bf16x8*)&lds[kb_ + (s*2 + 1)*512 + lane*8];
                f32x4 d = {0.f,0.f,0.f,0.f};
                d = mfma16(kf0, qf0, d); d = mfma16(kf1, qf1, d);
                float pv[4];
                if (k0 < qbase) {
                    #pragma unroll
                    for (int r = 0; r < 4; ++r) { pv[r] = __expf(beta * d[r]); s2 += pv[r]; }
                } else {
                    int kb = k0 + lg*4;
                    #pragma unroll
                    for (int r = 0; r < 4; ++r) {
                        pv[r] = (kb + r <= qa) ? __expf(beta * d[r]) : 0.f; s2 += pv[r];
                    }
                }
                union { short4v s4; u32 uu[2]; } pb;
                pb.uu[0] = pack2bf(pv[0], pv[1]);
                pb.uu[1] = pack2bf(pv[2], pv[3]);
                short4v vf0 = *(const short4v*)&lds[vb_ + ((s*4 + 0)*64 + lane)*4];
                short4v vf1 = *(const short4v*)&lds[vb_ + ((s*4 + 1)*64 + lane)*4];
                short4v vf2 = *(const short4v*)&lds[vb_ + ((s*4 + 2)*64 + lane)*4];
                short4v vf3 = *(const short4v*)&lds[vb_ + ((s*4 + 3)*64 + lane)*4];
                o0 = mfma16k16(vf0, pb.s4, o0);
                o1 = mfma16k16(vf1, pb.s4, o1);
                o2 = mfma16k16(vf2, pb.s4, o2);
                o3 = mfma16k16(vf3, pb.s4, o3);
            }
        }
    }
    s2 += __shfl_xor(s2, 16); s2 += __shfl_xor(s2, 32);
    float inv = 1.f / s2;

    size_t row = ((size_t)(b*2048 + qa))*1024 + h*64;
    f32x4 oo[4] = {o0, o1, o2, o3};
    #pragma unroll
    for (int dc = 0; dc < 4; ++dc) {
        short4v wv;
        #pragma unroll
        for (int r = 0; r < 4; ++r) wv[r] = f2bf(oo[dc][r] * inv);
        *(short4v*)&AO[row + dc*16 + lg*4] = wv;
    }
}

// ---------- launch ----------
extern "C" void kernel_launch(void* const* d_in, const int* in_sizes, int n_in,
                              void* d_out, int out_size, void* d_ws, size_t ws_size,
                              hipStream_t stream) {
    const float* x  = (const float*)d_in[0];
    const float* Wq = (const float*)d_in[1];
    const float* Wk = (const float*)d_in[2];
    const float* Wv = (const float*)d_in[3];
    const float* Wo = (const float*)d_in[4];
    const float* bo = (const float*)d_in[5];
    float* out = (float*)d_out;
    short* ws = (short*)d_ws;

    short* xb  = ws;              // [4096][1024] bf16 x
    short* wqb = ws + 4194304;
    short* wkb = ws + 5242880;
    short* wvb = ws + 6291456;
    short* wob = ws + 7340032;
    short* Qh  = ws + 8388608;    // [2][16][2048][64], scaled by 0.125
    short* Kh  = ws + 12582912;   // [2][16][2048][64]
    short* Vf  = ws + 16777216;   // [32 bh][32 chunks][4096] PV-fragment order
    short* AO  = ws + 20971520;   // [4096][1024] attention output

    cvt_all_kernel<<<8192, 256, 0, stream>>>(x, Wq, Wk, Wv, Wo, ws);
    gemm_qkv_kernel<<<dim3(24, 32), 256, 0, stream>>>(xb, wqb, wkb, wvb, Qh, Kh, Vf);
    attn_kernel<<<1024, 256, 0, stream>>>(Qh, Kh, Vf, AO);
    gemm_out_kernel<<<dim3(8, 64), 256, 0, stream>>>(AO, wob, bo, out);
}